// Round 1
// baseline (73775.732 us; speedup 1.0000x reference)
//
#include <hip/hip_runtime.h>

// NCA model constants (match reference)
#define BB   16
#define HH   128
#define WW   128
#define CC   64
#define FAN  192   // C * (NFILT+1)
#define HID  256
#define TP   32    // pixels per block
#define NTH  256
#define STEPS 8

__device__ __forceinline__ int reflect_idx(int i, int n) {
    if (i < 0) return -i;            // -1 -> 1 (jnp.pad 'reflect')
    if (i >= n) return 2 * n - 2 - i; // n -> n-2
    return i;
}

__global__ __launch_bounds__(256) void nca_step(
    const float* __restrict__ src, float* __restrict__ dst,
    const float* __restrict__ w1, const float* __restrict__ w2,
    const float* __restrict__ wh, const float* __restrict__ bh,
    const float* __restrict__ wf, const float* __restrict__ rnd)
{
    __shared__ float xs[3][TP + 2][CC];   // 26112 B: rows h-1..h+1, cols w0-1..w0+TP
    __shared__ float Fs[TP][FAN + 4];     // 25088 B: stride 196 floats (16B-aligned rows)
    __shared__ float cwf[2 * 576];        //  4608 B: both depthwise kernels
    __shared__ float dxs[TP][65];         //  8320 B: dx accumulator (+1 pad)

    const int tid = threadIdx.x;
    const int w0  = blockIdx.x * TP;
    const int h   = blockIdx.y;
    const int b   = blockIdx.z;

    // ---- phase 1: halo load (3 rows x 34 cols x 64 ch), reflect-padded ----
    for (int i = tid; i < 3 * (TP + 2) * (CC / 4); i += NTH) {
        const int r   = i / ((TP + 2) * (CC / 4));
        const int rem = i - r * ((TP + 2) * (CC / 4));
        const int wi  = rem >> 4;
        const int c4  = (rem & 15) * 4;
        const int sr  = reflect_idx(h - 1 + r, HH);
        const int sc  = reflect_idx(w0 - 1 + wi, WW);
        const float4 v = *(const float4*)&src[(((size_t)b * HH + sr) * WW + sc) * CC + c4];
        *(float4*)&xs[r][wi][c4] = v;
    }
    for (int i = tid; i < 1152; i += NTH)
        cwf[i] = (i < 576) ? w1[i] : w2[i - 576];
    for (int i = tid; i < TP * 65; i += NTH)
        (&dxs[0][0])[i] = 0.f;
    __syncthreads();

    // ---- phase 2: build features F = [x, dwconv1(x), dwconv2(x)] ----
    {
        const int p  = tid >> 3;         // 0..31 pixel in tile
        const int cg = (tid & 7) * 8;    // 8 channels per thread
        for (int cc = 0; cc < 8; ++cc) {
            const int c = cg + cc;
            float a1 = 0.f, a2 = 0.f;
            #pragma unroll
            for (int j = 0; j < 3; ++j)       // h-offset
                #pragma unroll
                for (int i2 = 0; i2 < 3; ++i2) { // w-offset
                    const float v = xs[j][p + i2][c];
                    a1 = fmaf(v, cwf[c * 9 + i2 * 3 + j], a1);
                    a2 = fmaf(v, cwf[576 + c * 9 + i2 * 3 + j], a2);
                }
            Fs[p][c]        = xs[1][p + 1][c];
            Fs[p][64 + c]   = a1;
            Fs[p][128 + c]  = a2;
        }
    }
    __syncthreads();

    // ---- phase 3: hidden = relu(Wh F + b); dx_partial = Wf^T hidden ----
    {
        const int p = tid >> 3;  // pixel 0..31
        const int q = tid & 7;   // hidden slice: o in [32q, 32q+32)
        float dxp[64];
        #pragma unroll
        for (int c = 0; c < 64; ++c) dxp[c] = 0.f;

        #pragma unroll
        for (int og = 0; og < 2; ++og) {
            const int ob = q * 32 + og * 16;
            float hacc[16];
            #pragma unroll
            for (int k = 0; k < 16; ++k) hacc[k] = bh[ob + k];
            for (int f4 = 0; f4 < 48; ++f4) {
                const float4 fv = *(const float4*)&Fs[p][f4 * 4];
                #pragma unroll
                for (int k = 0; k < 16; ++k) {
                    const float4 wv = *(const float4*)&wh[(ob + k) * FAN + f4 * 4];
                    hacc[k] = fmaf(fv.x, wv.x, hacc[k]);
                    hacc[k] = fmaf(fv.y, wv.y, hacc[k]);
                    hacc[k] = fmaf(fv.z, wv.z, hacc[k]);
                    hacc[k] = fmaf(fv.w, wv.w, hacc[k]);
                }
            }
            #pragma unroll
            for (int k = 0; k < 16; ++k) hacc[k] = fmaxf(hacc[k], 0.f);
            #pragma unroll
            for (int k4 = 0; k4 < 4; ++k4) {
                #pragma unroll
                for (int c = 0; c < 64; ++c) {
                    const float4 wv = *(const float4*)&wf[c * HID + ob + k4 * 4];
                    dxp[c] = fmaf(hacc[k4 * 4 + 0], wv.x, dxp[c]);
                    dxp[c] = fmaf(hacc[k4 * 4 + 1], wv.y, dxp[c]);
                    dxp[c] = fmaf(hacc[k4 * 4 + 2], wv.z, dxp[c]);
                    dxp[c] = fmaf(hacc[k4 * 4 + 3], wv.w, dxp[c]);
                }
            }
        }
        // deterministic round-robin reduction over the 8 hidden slices
        for (int r = 0; r < 8; ++r) {
            if (q == r) {
                #pragma unroll
                for (int c = 0; c < 64; ++c) dxs[p][c] += dxp[c];
            }
            __syncthreads();
        }
    }

    // ---- phase 4: stochastic gate + channel mask + life mask + store ----
    for (int i = tid; i < TP * 16; i += NTH) {
        const int p  = i >> 4;
        const int c4 = (i & 15) * 4;
        const int w  = w0 + p;
        const size_t pix = ((size_t)b * HH + h) * WW + w;
        const float g  = (rnd[pix] > 0.5f) ? 1.f : 0.f;
        const float mg = (c4 == 0) ? 0.f : g;   // channels 0..3 immutable
        const float4 xv = *(const float4*)&src[pix * CC + c4];
        float4 ov;
        ov.x = xv.x + dxs[p][c4 + 0] * mg;
        ov.y = xv.y + dxs[p][c4 + 1] * mg;
        ov.z = xv.z + dxs[p][c4 + 2] * mg;
        ov.w = xv.w + dxs[p][c4 + 3] * mg;
        const float x0   = xs[1][p + 1][0];     // new ch0 == old ch0 (masked)
        const float life = (x0 > 0.f) ? 1.f : 0.f;
        ov.x *= life; ov.y *= life; ov.z *= life; ov.w *= life;
        *(float4*)&dst[pix * CC + c4] = ov;
    }
}

extern "C" void kernel_launch(void* const* d_in, const int* in_sizes, int n_in,
                              void* d_out, int out_size, void* d_ws, size_t ws_size,
                              hipStream_t stream) {
    const float* x  = (const float*)d_in[0];
    const float* w1 = (const float*)d_in[1];
    const float* w2 = (const float*)d_in[2];
    const float* wh = (const float*)d_in[3];
    const float* bh = (const float*)d_in[4];
    const float* wf = (const float*)d_in[5];
    const float* rv = (const float*)d_in[6];
    // d_in[7] = steps (always 8, matches rand_vals dim 0)

    float* A  = (float*)d_ws;    // step parity: even steps write A, odd write B
    float* Bq = (float*)d_out;   // step 7 (last) writes d_out

    dim3 grid(WW / TP, HH, BB), block(NTH);
    for (int s = 0; s < STEPS; ++s) {
        const float* srcp = (s == 0) ? x : ((s & 1) ? A : Bq);
        float* dstp = (s & 1) ? Bq : A;
        hipLaunchKernelGGL(nca_step, grid, block, 0, stream,
                           srcp, dstp, w1, w2, wh, bh, wf,
                           rv + (size_t)s * BB * HH * WW);
    }
}

// Round 2
// 2219.128 us; speedup vs baseline: 33.2454x; 33.2454x over previous
//
#include <hip/hip_runtime.h>

#define BB 16
#define HH 128
#define WW 128
#define SC 60              // compact state channels (ch 4..63)
#define PXB 64             // pixels per block
#define NPIX (BB*HH*WW)
#define KTOT 576           // 9 taps * 64 ch

typedef __attribute__((ext_vector_type(8))) short short8;
typedef __attribute__((ext_vector_type(8))) unsigned short ushort8;
typedef __attribute__((ext_vector_type(4))) float f4;

__device__ __forceinline__ unsigned short f2b(float f) {   // fp32 -> bf16 RTNE
    unsigned x = __float_as_uint(f);
    x += 0x7fffu + ((x >> 16) & 1u);
    return (unsigned short)(x >> 16);
}

__device__ __forceinline__ int refl(int i, int n) {
    if (i < 0) return -i;
    if (i >= n) return 2*n - 2 - i;
    return i;
}

// ---- prep: W~[o][tap*64+c] (bf16 [256][576]) and wf (bf16 [64][256]) ----
__global__ __launch_bounds__(256) void prep(
    const float* __restrict__ w1, const float* __restrict__ w2,
    const float* __restrict__ wh, const float* __restrict__ wf,
    unsigned short* __restrict__ wt, unsigned short* __restrict__ wfb)
{
    int i = blockIdx.x * 256 + threadIdx.x;
    if (i < 256 * KTOT) {
        int o = i / KTOT, k = i - o * KTOT;
        int t = k >> 6, c = k & 63;
        int tj = t / 3, tw = t % 3;          // tj = h-offset idx, tw = w-offset idx
        float kv = w1[c*9 + tw*3 + tj];
        float kv2 = w2[c*9 + tw*3 + tj];
        float v = wh[o*192 + 64 + c] * kv + wh[o*192 + 128 + c] * kv2;
        if (t == 4) v += wh[o*192 + c];      // identity tap (j=1,i=1)
        wt[o*KTOT + k] = f2b(v);
    } else {
        int j = i - 256 * KTOT;              // j < 64*256
        wfb[j] = f2b(wf[j]);
    }
}

// MODE 0: src = xin (64ch raw); dst = state (60ch)
// MODE 1: src = state (60ch);   dst = state (60ch)
// MODE 2: src = state (60ch);   dst = out (64ch, final)
template<int MODE>
__global__ __launch_bounds__(512, 2) void nca_step(
    const float* xin, const float* src, float* __restrict__ dst,
    const unsigned short* __restrict__ wt, const unsigned short* __restrict__ wfb,
    const float* __restrict__ bh, const float* __restrict__ rnd)
{
    __shared__ __align__(16) char smem[65376];
    unsigned short (*xsb)[66][72] = (unsigned short(*)[66][72])smem;  // 28512 B
    char* wtcB = smem + 28512;                                        // 36864 B (swizzled)
    unsigned short* hs = (unsigned short*)smem;                       // [64][264] alias, 33792 B

    const int tid = threadIdx.x;
    const int w0 = blockIdx.x * PXB;
    const int h  = blockIdx.y;
    const int b  = blockIdx.z;
    const int lane = tid & 63, wv = tid >> 6;
    const int lr = lane & 15, lg = lane >> 4;
    const int pw = wv & 3, ow = wv >> 2;

    // ---- phase 1: halo (3 rows x 66 cols x 64 ch) -> bf16 LDS ----
    for (int s = tid >> 2; s < 198; s += 128) {
        const int r3 = s / 66, wi = s - r3 * 66;
        const int q = tid & 3;                       // 16-channel group
        const int sr = refl(h - 1 + r3, HH);
        const int sc = refl(w0 - 1 + wi, WW);
        const size_t pix = ((size_t)b * HH + sr) * WW + sc;
        float v[16];
        if (MODE == 0) {
            const float* p = xin + pix * 64 + q * 16;
            #pragma unroll
            for (int t4 = 0; t4 < 4; ++t4) {
                f4 a = *(const f4*)(p + t4 * 4);
                v[t4*4+0]=a.x; v[t4*4+1]=a.y; v[t4*4+2]=a.z; v[t4*4+3]=a.w;
            }
        } else {
            if (q == 0) {
                f4 x4 = *(const f4*)(xin + pix * 64);
                const float life = (x4.x > 0.f) ? 1.f : 0.f;
                v[0]=x4.x*life; v[1]=x4.y*life; v[2]=x4.z*life; v[3]=x4.w*life;
                #pragma unroll
                for (int t4 = 0; t4 < 3; ++t4) {
                    f4 a = *(const f4*)(src + pix * SC + t4 * 4);
                    v[4+t4*4+0]=a.x; v[4+t4*4+1]=a.y; v[4+t4*4+2]=a.z; v[4+t4*4+3]=a.w;
                }
            } else {
                const float* p = src + pix * SC + q * 16 - 4;
                #pragma unroll
                for (int t4 = 0; t4 < 4; ++t4) {
                    f4 a = *(const f4*)(p + t4 * 4);
                    v[t4*4+0]=a.x; v[t4*4+1]=a.y; v[t4*4+2]=a.z; v[t4*4+3]=a.w;
                }
            }
        }
        ushort8 o0, o1;
        #pragma unroll
        for (int k = 0; k < 8; ++k) { o0[k] = f2b(v[k]); o1[k] = f2b(v[8 + k]); }
        *(ushort8*)&xsb[r3][wi][q * 16]     = o0;
        *(ushort8*)&xsb[r3][wi][q * 16 + 8] = o1;
    }

    // prefetch W~ chunk 0 while halo completes
    f4 stg[5];
    #pragma unroll
    for (int it = 0; it < 5; ++it) {
        int u = tid + it * 512;
        if (u < 2304) stg[it] = *(const f4*)((const char*)wt + (size_t)u * 16);
    }
    __syncthreads();

    // ---- A fragments (registers): K = tap*64 + c, read shifted halo ----
    short8 afr[18];
    #pragma unroll
    for (int kc = 0; kc < 18; ++kc) {
        const int t = kc >> 1, c0 = (kc & 1) * 32 + lg * 8;
        const int tj = t / 3, ti = t % 3;
        afr[kc] = *(const short8*)&xsb[tj][pw * 16 + lr + ti][c0];
    }

    // ---- GEMM1: hidden = relu(W~ . xhalo + b), chunked over o ----
    f4 acc[8];
    const int orow = ow * 16 + lr;
    #pragma unroll
    for (int ch = 0; ch < 8; ++ch) {
        if (ch > 0) __syncthreads();
        #pragma unroll
        for (int it = 0; it < 5; ++it) {            // store chunk (swizzled)
            int u = tid + it * 512;
            if (u < 2304) {
                int row = u / 72, c16 = u - row * 72;
                int off = (row * 1152 + c16 * 16) ^ ((row & 7) << 4);
                *(f4*)(wtcB + off) = stg[it];
            }
        }
        __syncthreads();
        if (ch < 7) {                                // prefetch next chunk
            #pragma unroll
            for (int it = 0; it < 5; ++it) {
                int u = tid + it * 512;
                if (u < 2304)
                    stg[it] = *(const f4*)((const char*)wt + (size_t)(ch + 1) * 36864 + (size_t)u * 16);
            }
        }
        const float bias = bh[(2 * ch + ow) * 16 + lr];
        f4 a0 = {bias, bias, bias, bias};
        f4 a1 = {0.f, 0.f, 0.f, 0.f};
        #pragma unroll
        for (int kc = 0; kc < 18; kc += 2) {
            const short8 b0 = *(const short8*)(wtcB + ((orow * 1152 + kc * 64 + lg * 16) ^ ((orow & 7) << 4)));
            const short8 b1 = *(const short8*)(wtcB + ((orow * 1152 + (kc + 1) * 64 + lg * 16) ^ ((orow & 7) << 4)));
            a0 = __builtin_amdgcn_mfma_f32_16x16x32_bf16(afr[kc],     b0, a0, 0, 0, 0);
            a1 = __builtin_amdgcn_mfma_f32_16x16x32_bf16(afr[kc + 1], b1, a1, 0, 0, 0);
        }
        acc[ch] = a0 + a1;
    }

    __syncthreads();   // all waves done with xsb/wtc -> reuse as hs
    #pragma unroll
    for (int ch = 0; ch < 8; ++ch) {
        const int o = (2 * ch + ow) * 16 + lr;
        #pragma unroll
        for (int r = 0; r < 4; ++r)
            hs[(pw * 16 + lg * 4 + r) * 264 + o] = f2b(fmaxf(acc[ch][r], 0.f));
    }
    __syncthreads();

    // ---- GEMM2: dx = h . wf^T ----
    short8 ha[8];
    #pragma unroll
    for (int kk = 0; kk < 8; ++kk)
        ha[kk] = *(const short8*)&hs[(pw * 16 + lr) * 264 + kk * 32 + lg * 8];
    f4 acc2[2] = {{0.f,0.f,0.f,0.f}, {0.f,0.f,0.f,0.f}};
    #pragma unroll
    for (int ct2 = 0; ct2 < 2; ++ct2) {
        const int c = (ow * 2 + ct2) * 16 + lr;
        #pragma unroll
        for (int kk = 0; kk < 8; ++kk) {
            const short8 bf = *(const short8*)&wfb[c * 256 + kk * 32 + lg * 8];
            acc2[ct2] = __builtin_amdgcn_mfma_f32_16x16x32_bf16(ha[kk], bf, acc2[ct2], 0, 0, 0);
        }
    }

    // ---- epilogue: gate + channel mask + life + store ----
    #pragma unroll
    for (int r = 0; r < 4; ++r) {
        const int p = pw * 16 + lg * 4 + r;
        const size_t pix = ((size_t)b * HH + h) * WW + (w0 + p);
        const float life = (xin[pix * 64] > 0.f) ? 1.f : 0.f;
        const float g = (rnd[pix] > 0.5f) ? 1.f : 0.f;
        #pragma unroll
        for (int ct2 = 0; ct2 < 2; ++ct2) {
            const int c = (ow * 2 + ct2) * 16 + lr;
            const float dx = acc2[ct2][r];
            float base;
            if (MODE == 0) base = xin[pix * 64 + c];
            else base = (c < 4) ? xin[pix * 64 + c] * life : src[pix * SC + (c - 4)];
            const float outv = (c >= 4) ? (base + dx * g) * life : base * life;
            if (MODE == 2) dst[pix * 64 + c] = outv;
            else if (c >= 4) dst[pix * SC + (c - 4)] = outv;
        }
    }
}

extern "C" void kernel_launch(void* const* d_in, const int* in_sizes, int n_in,
                              void* d_out, int out_size, void* d_ws, size_t ws_size,
                              hipStream_t stream) {
    const float* xin = (const float*)d_in[0];
    const float* w1  = (const float*)d_in[1];
    const float* w2  = (const float*)d_in[2];
    const float* wh  = (const float*)d_in[3];
    const float* bh  = (const float*)d_in[4];
    const float* wf  = (const float*)d_in[5];
    const float* rv  = (const float*)d_in[6];

    const size_t stateBytes = (size_t)NPIX * SC * 4;     // 62,914,560
    unsigned short* wt  = (unsigned short*)((char*)d_ws + stateBytes);
    unsigned short* wfb = wt + 256 * KTOT;
    float* st = (float*)d_ws;
    float* om = (float*)d_out;

    prep<<<dim3(640), dim3(256), 0, stream>>>(w1, w2, wh, wf, wt, wfb);

    dim3 g(WW / PXB, HH, BB), blk(512);
    nca_step<0><<<g, blk, 0, stream>>>(xin, xin, st, wt, wfb, bh, rv);
    for (int s = 1; s < 7; ++s) {
        const float* sp = (s & 1) ? (const float*)st : (const float*)om;
        float* dp       = (s & 1) ? om : st;
        nca_step<1><<<g, blk, 0, stream>>>(xin, sp, dp, wt, wfb, bh, rv + (size_t)s * NPIX);
    }
    nca_step<2><<<g, blk, 0, stream>>>(xin, st, om, wt, wfb, bh, rv + (size_t)7 * NPIX);
}

// Round 3
// 1652.935 us; speedup vs baseline: 44.6332x; 1.3425x over previous
//
#include <hip/hip_runtime.h>

#define BB 16
#define HH 128
#define WW 128
#define SC 60              // compact state channels (ch 4..63)
#define PXB 64             // pixels per block
#define NPIX (BB*HH*WW)
#define KF 192             // GEMM1 K (unfolded features)
#define HID 256

typedef __attribute__((ext_vector_type(8))) short short8;
typedef __attribute__((ext_vector_type(8))) unsigned short ushort8;
typedef __attribute__((ext_vector_type(4))) float f4;

// smem layout: [halo 28512][wcv 4608][F 24576][life/gate 512] = 58208
// h [64][256] bf16 swizzled (32768 B) overlays halo+wcv after F is built.
#define OFF_WCV 28512
#define OFF_F   33120
#define OFF_LG  57696
#define SMEM_SZ 58208

__device__ __forceinline__ unsigned short f2b(float f) {   // fp32 -> bf16 RTNE
    unsigned x = __float_as_uint(f);
    x += 0x7fffu + ((x >> 16) & 1u);
    return (unsigned short)(x >> 16);
}
__device__ __forceinline__ float b2f(unsigned short u) {
    return __uint_as_float(((unsigned)u) << 16);
}
__device__ __forceinline__ int refl(int i, int n) {
    if (i < 0) return -i;
    if (i >= n) return 2*n - 2 - i;
    return i;
}

// prep: cast wh -> bf16 [256][192], wf -> bf16 [64][256]
__global__ __launch_bounds__(256) void prep(
    const float* __restrict__ wh, const float* __restrict__ wf,
    unsigned short* __restrict__ whb, unsigned short* __restrict__ wfb)
{
    int i = blockIdx.x * 256 + threadIdx.x;   // 256 blocks
    if (i < 49152) whb[i] = f2b(wh[i]);
    else wfb[i - 49152] = f2b(wf[i - 49152]);
}

// MODE 0: src = xin (64ch raw); dst = state (60ch)
// MODE 1: src = state (60ch);   dst = state (60ch)
// MODE 2: src = state (60ch);   dst = out (64ch, final)
template<int MODE>
__global__ __launch_bounds__(512, 4) void nca_step(
    const float* __restrict__ xin, const float* __restrict__ src,
    float* __restrict__ dst,
    const unsigned short* __restrict__ whb, const unsigned short* __restrict__ wfb,
    const float* __restrict__ w1, const float* __restrict__ w2,
    const float* __restrict__ bh, const float* __restrict__ rnd)
{
    __shared__ __align__(16) char smem[SMEM_SZ];
    unsigned short (*xsb)[66][72] = (unsigned short(*)[66][72])smem;
    float* wcv = (float*)(smem + OFF_WCV);   // [2][9 taps][64 ch]
    float* lgs = (float*)(smem + OFF_LG);    // life[64], gate[64]

    const int tid = threadIdx.x;
    const int w0 = blockIdx.x * PXB;
    const int h  = blockIdx.y;
    const int b  = blockIdx.z;

    // ---- phase 1: halo (3 x 66 x 64ch) -> bf16 LDS; conv weights; life/gate ----
    for (int s = tid >> 2; s < 198; s += 128) {
        const int r3 = s / 66, wi = s - r3 * 66;
        const int q = tid & 3;                       // 16-channel group
        const int sr = refl(h - 1 + r3, HH);
        const int sc = refl(w0 - 1 + wi, WW);
        const size_t pix = ((size_t)b * HH + sr) * WW + sc;
        float v[16];
        if (MODE == 0) {
            const float* p = xin + pix * 64 + q * 16;
            #pragma unroll
            for (int t4 = 0; t4 < 4; ++t4) {
                f4 a = *(const f4*)(p + t4 * 4);
                v[t4*4+0]=a.x; v[t4*4+1]=a.y; v[t4*4+2]=a.z; v[t4*4+3]=a.w;
            }
        } else {
            if (q == 0) {
                f4 x4 = *(const f4*)(xin + pix * 64);
                const float life = (x4.x > 0.f) ? 1.f : 0.f;
                v[0]=x4.x*life; v[1]=x4.y*life; v[2]=x4.z*life; v[3]=x4.w*life;
                #pragma unroll
                for (int t4 = 0; t4 < 3; ++t4) {
                    f4 a = *(const f4*)(src + pix * SC + t4 * 4);
                    v[4+t4*4+0]=a.x; v[4+t4*4+1]=a.y; v[4+t4*4+2]=a.z; v[4+t4*4+3]=a.w;
                }
            } else {
                const float* p = src + pix * SC + q * 16 - 4;
                #pragma unroll
                for (int t4 = 0; t4 < 4; ++t4) {
                    f4 a = *(const f4*)(p + t4 * 4);
                    v[t4*4+0]=a.x; v[t4*4+1]=a.y; v[t4*4+2]=a.z; v[t4*4+3]=a.w;
                }
            }
        }
        ushort8 o0, o1;
        #pragma unroll
        for (int k = 0; k < 8; ++k) { o0[k] = f2b(v[k]); o1[k] = f2b(v[8 + k]); }
        *(ushort8*)&xsb[r3][wi][q * 16]     = o0;
        *(ushort8*)&xsb[r3][wi][q * 16 + 8] = o1;
    }
    // conv weights transposed to [filter][tap][c]
    for (int i = tid; i < 1152; i += 512) {
        const int f = i / 576, rem = i - f * 576;
        const int t = rem >> 6, c = rem & 63;
        wcv[f*576 + t*64 + c] = (f ? w2 : w1)[c*9 + t];
    }
    if (tid < 64) {
        const size_t pix = ((size_t)b*HH + h)*WW + w0 + tid;
        lgs[tid]      = (xin[pix*64] > 0.f) ? 1.f : 0.f;
        lgs[64 + tid] = (rnd[pix] > 0.5f) ? 1.f : 0.f;
    }
    __syncthreads();

    // ---- phase 2: F = [x | dwconv1 | dwconv2], bf16, XOR-swizzled rows ----
    {
        const int px = tid >> 3;
        const int cg = (tid & 7) * 8;
        const int sw = (px & 7) << 4;
        *(ushort8*)(smem + (OFF_F + ((px*384 + cg*2) ^ sw))) = *(ushort8*)&xsb[1][px+1][cg];
        float a1[8], a2[8];
        #pragma unroll
        for (int k = 0; k < 8; ++k) { a1[k]=0.f; a2[k]=0.f; }
        #pragma unroll
        for (int t = 0; t < 9; ++t) {                // t = i*3 + j (w-off i, h-off j)
            const int i2 = t / 3, j = t - 3*i2;
            const ushort8 xv = *(ushort8*)&xsb[j][px + i2][cg];
            #pragma unroll
            for (int k = 0; k < 8; ++k) {
                const float v = b2f(xv[k]);
                a1[k] = fmaf(v, wcv[t*64 + cg + k], a1[k]);
                a2[k] = fmaf(v, wcv[576 + t*64 + cg + k], a2[k]);
            }
        }
        ushort8 o1, o2;
        #pragma unroll
        for (int k = 0; k < 8; ++k) { o1[k] = f2b(a1[k]); o2[k] = f2b(a2[k]); }
        *(ushort8*)(smem + (OFF_F + ((px*384 + (64+cg)*2) ^ sw))) = o1;
        *(ushort8*)(smem + (OFF_F + ((px*384 + (128+cg)*2) ^ sw))) = o2;
    }
    __syncthreads();

    // ---- phase 3: GEMM1 h = relu(F . Wh^T + b), wave tile = 2 Mt x 4 Ot ----
    const int l  = tid & 63, wv = tid >> 6;
    const int lr = l & 15, gq = l >> 4;
    const int ms = wv >> 2, os = wv & 3;     // ms: px half, os: 64-o slice

    f4 acc[2][4];
    #pragma unroll
    for (int ot = 0; ot < 4; ++ot) {
        const float bv = bh[os*64 + ot*16 + lr];
        const f4 bvv = {bv, bv, bv, bv};
        acc[0][ot] = bvv; acc[1][ot] = bvv;
    }
    #pragma unroll
    for (int ks = 0; ks < 6; ++ks) {
        short8 afr[2];
        #pragma unroll
        for (int mt = 0; mt < 2; ++mt) {
            const int px = ms*32 + mt*16 + lr;
            afr[mt] = *(const short8*)(smem + (OFF_F + ((px*384 + ks*64 + gq*16) ^ ((px&7)<<4))));
        }
        #pragma unroll
        for (int ot = 0; ot < 4; ++ot) {
            const short8 bfr = *(const short8*)(whb + (os*64 + ot*16 + lr)*KF + ks*32 + gq*8);
            acc[0][ot] = __builtin_amdgcn_mfma_f32_16x16x32_bf16(afr[0], bfr, acc[0][ot], 0,0,0);
            acc[1][ot] = __builtin_amdgcn_mfma_f32_16x16x32_bf16(afr[1], bfr, acc[1][ot], 0,0,0);
        }
    }
    // relu + bf16 h into LDS (overlays dead halo/wcv), swizzled rows of 512 B
    #pragma unroll
    for (int mt = 0; mt < 2; ++mt)
      #pragma unroll
      for (int ot = 0; ot < 4; ++ot)
        #pragma unroll
        for (int r = 0; r < 4; ++r) {
            const int px = ms*32 + mt*16 + gq*4 + r;
            const int o  = os*64 + ot*16 + lr;
            *(unsigned short*)(smem + ((px*512 + o*2) ^ ((px&7)<<4))) =
                f2b(fmaxf(acc[mt][ot][r], 0.f));
        }
    __syncthreads();

    // ---- phase 4: GEMM2 dx = h . wf^T, wave tile = 1 Mt x 2 Ct ----
    const int mt2 = wv >> 1;                 // px tile 0..3
    const int cs  = wv & 1;                  // c half
    f4 acc2[2] = {{0.f,0.f,0.f,0.f},{0.f,0.f,0.f,0.f}};
    #pragma unroll
    for (int ks = 0; ks < 8; ++ks) {
        const int px = mt2*16 + lr;
        const short8 ha = *(const short8*)(smem + ((px*512 + ks*64 + gq*16) ^ ((px&7)<<4)));
        #pragma unroll
        for (int ct = 0; ct < 2; ++ct) {
            const short8 bw = *(const short8*)(wfb + (cs*32 + ct*16 + lr)*HID + ks*32 + gq*8);
            acc2[ct] = __builtin_amdgcn_mfma_f32_16x16x32_bf16(ha, bw, acc2[ct], 0,0,0);
        }
    }

    // ---- epilogue: gate + channel mask + life + store ----
    #pragma unroll
    for (int ct = 0; ct < 2; ++ct)
      #pragma unroll
      for (int r = 0; r < 4; ++r) {
        const int px = mt2*16 + gq*4 + r;
        const int c  = cs*32 + ct*16 + lr;
        const size_t pix = ((size_t)b*HH + h)*WW + w0 + px;
        const float life = lgs[px], g = lgs[64 + px];
        const float dx = acc2[ct][r];
        float base;
        if (MODE == 0) base = xin[pix*64 + c];
        else base = (c < 4) ? xin[pix*64 + c] * life : src[pix*SC + (c-4)];
        const float outv = (c >= 4) ? (base + dx*g)*life : base*life;
        if (MODE == 2) dst[pix*64 + c] = outv;
        else if (c >= 4) dst[pix*SC + (c-4)] = outv;
    }
}

extern "C" void kernel_launch(void* const* d_in, const int* in_sizes, int n_in,
                              void* d_out, int out_size, void* d_ws, size_t ws_size,
                              hipStream_t stream) {
    const float* xin = (const float*)d_in[0];
    const float* w1  = (const float*)d_in[1];
    const float* w2  = (const float*)d_in[2];
    const float* wh  = (const float*)d_in[3];
    const float* bh  = (const float*)d_in[4];
    const float* wf  = (const float*)d_in[5];
    const float* rv  = (const float*)d_in[6];

    const size_t stateBytes = (size_t)NPIX * SC * 4;
    unsigned short* whb = (unsigned short*)((char*)d_ws + stateBytes);
    unsigned short* wfb = whb + 256 * KF;
    float* st = (float*)d_ws;
    float* om = (float*)d_out;

    prep<<<dim3(256), dim3(256), 0, stream>>>(wh, wf, whb, wfb);

    dim3 g(WW / PXB, HH, BB), blk(512);
    nca_step<0><<<g, blk, 0, stream>>>(xin, xin, st, whb, wfb, w1, w2, bh, rv);
    for (int s = 1; s < 7; ++s) {
        const float* sp = (s & 1) ? (const float*)st : (const float*)om;
        float* dp       = (s & 1) ? om : st;
        nca_step<1><<<g, blk, 0, stream>>>(xin, sp, dp, whb, wfb, w1, w2, bh, rv + (size_t)s * NPIX);
    }
    nca_step<2><<<g, blk, 0, stream>>>(xin, st, om, whb, wfb, w1, w2, bh, rv + (size_t)7 * NPIX);
}

// Round 4
// 1302.906 us; speedup vs baseline: 56.6240x; 1.2687x over previous
//
#include <hip/hip_runtime.h>

#define BB 16
#define HH 128
#define WW 128
#define SC 60              // compact state channels (ch 4..63)
#define TPX 32             // tile width in pixels
#define NPIX (BB*HH*WW)
#define KF 192
#define HID 256

typedef __attribute__((ext_vector_type(8))) short short8;
typedef __attribute__((ext_vector_type(8))) unsigned short ushort8;
typedef __attribute__((ext_vector_type(4))) float f4;

// LDS layout (bytes):
//   xsb  [3][34][66] ushort  @ 0      : 13,464
//   Fc   [32][128]   ushort  @ 13,472 :  8,192  (XOR-swizzled rows)
//   wcvb [2][9][64]  ushort  @ 21,664 :  2,304
//   lgs  [64]        float   @ 23,968 :    256
//   h    [32][256]   ushort  @ 0      : 16,384  (overlay after GEMM1)
#define OFF_FC  13472
#define OFF_WCV 21664
#define OFF_LG  23968
#define SMEM_SZ 24224

__device__ __forceinline__ unsigned short f2b(float f) {   // fp32 -> bf16 RTNE
    unsigned x = __float_as_uint(f);
    x += 0x7fffu + ((x >> 16) & 1u);
    return (unsigned short)(x >> 16);
}
__device__ __forceinline__ float b2f(unsigned short u) {
    return __uint_as_float(((unsigned)u) << 16);
}
__device__ __forceinline__ int refl(int i, int n) {
    if (i < 0) return -i;
    if (i >= n) return 2*n - 2 - i;
    return i;
}

// prep: weights into MFMA B-fragment order (bf16).
// wtp: GEMM1, group g = ((os*4+ot)*6+ks)*64 + lane, 8 shorts each.
// wfp: GEMM2, group g = ((cs*2+ct)*8+ks2)*64 + lane.
__global__ __launch_bounds__(256) void prep(
    const float* __restrict__ wh, const float* __restrict__ wf,
    unsigned short* __restrict__ wtp, unsigned short* __restrict__ wfp)
{
    int i = blockIdx.x * 256 + threadIdx.x;   // 8192 groups
    if (i < 6144) {
        const int l = i & 63, r = i >> 6;
        const int ks = r % 6, r2 = r / 6;
        const int ot = r2 & 3, os = r2 >> 2;
        const int row = os*64 + ot*16 + (l & 15);
        const int k0  = ks*32 + (l >> 4)*8;
        ushort8 v;
        #pragma unroll
        for (int j = 0; j < 8; ++j) v[j] = f2b(wh[row*KF + k0 + j]);
        *(ushort8*)&wtp[(size_t)i * 8] = v;
    } else {
        const int g = i - 6144;               // 2048 groups
        const int l = g & 63, r = g >> 6;
        const int ks2 = r & 7, r2 = r >> 3;
        const int ct = r2 & 1, cs = r2 >> 1;
        const int c  = cs*32 + ct*16 + (l & 15);
        const int o0 = ks2*32 + (l >> 4)*8;
        ushort8 v;
        #pragma unroll
        for (int j = 0; j < 8; ++j) v[j] = f2b(wf[c*HID + o0 + j]);
        *(ushort8*)&wfp[(size_t)g * 8] = v;
    }
}

// MODE 0: src = xin (64ch raw); dst = state (60ch)
// MODE 1: src = state (60ch);   dst = state (60ch)
// MODE 2: src = state (60ch);   dst = out (64ch, final)
template<int MODE>
__global__ __launch_bounds__(256, 6) void nca_step(
    const float* __restrict__ xin, const float* __restrict__ src,
    float* __restrict__ dst,
    const unsigned short* __restrict__ wtp, const unsigned short* __restrict__ wfp,
    const float* __restrict__ w1, const float* __restrict__ w2,
    const float* __restrict__ bh, const float* __restrict__ rnd)
{
    __shared__ __align__(16) char smem[SMEM_SZ];
    unsigned short* xs   = (unsigned short*)smem;
    unsigned short* wcvb = (unsigned short*)(smem + OFF_WCV);
    float*          lgs  = (float*)(smem + OFF_LG);

    const int tid = threadIdx.x;
    const int w0 = blockIdx.x * TPX;
    const int h  = blockIdx.y;
    const int b  = blockIdx.z;

    // ---- phase 1: conv weights, life/gate, halo (3 x 34 x 64ch) -> bf16 LDS ----
    for (int i = tid; i < 1152; i += 256) {
        const int f = i / 576, rem = i - f * 576;
        const int t = rem >> 6, c = rem & 63;
        wcvb[f*576 + t*64 + c] = f2b((f ? w2 : w1)[c*9 + t]);
    }
    if (tid < TPX) {
        const size_t pix = ((size_t)b*HH + h)*WW + w0 + tid;
        lgs[tid]       = (xin[pix*64] > 0.f) ? 1.f : 0.f;
        lgs[TPX + tid] = (rnd[pix] > 0.5f) ? 1.f : 0.f;
    }
    for (int s0 = tid >> 2; s0 < 102; s0 += 64) {
        const int r3 = s0 / 34, wi = s0 - r3*34;
        const int q = tid & 3;                    // 16-channel group
        const int sr = refl(h - 1 + r3, HH);
        const int sc = refl(w0 - 1 + wi, WW);
        const size_t pix = ((size_t)b*HH + sr)*WW + sc;
        float v[16];
        if (MODE == 0) {
            const float* p = xin + pix*64 + q*16;
            #pragma unroll
            for (int t4 = 0; t4 < 4; ++t4) {
                f4 a = *(const f4*)(p + t4*4);
                v[t4*4+0]=a.x; v[t4*4+1]=a.y; v[t4*4+2]=a.z; v[t4*4+3]=a.w;
            }
        } else {
            if (q == 0) {
                f4 x4 = *(const f4*)(xin + pix*64);
                const float life = (x4.x > 0.f) ? 1.f : 0.f;
                v[0]=x4.x*life; v[1]=x4.y*life; v[2]=x4.z*life; v[3]=x4.w*life;
                #pragma unroll
                for (int t4 = 0; t4 < 3; ++t4) {
                    f4 a = *(const f4*)(src + pix*SC + t4*4);
                    v[4+t4*4+0]=a.x; v[4+t4*4+1]=a.y; v[4+t4*4+2]=a.z; v[4+t4*4+3]=a.w;
                }
            } else {
                const float* p = src + pix*SC + q*16 - 4;
                #pragma unroll
                for (int t4 = 0; t4 < 4; ++t4) {
                    f4 a = *(const f4*)(p + t4*4);
                    v[t4*4+0]=a.x; v[t4*4+1]=a.y; v[t4*4+2]=a.z; v[t4*4+3]=a.w;
                }
            }
        }
        ushort8 o0, o1;
        #pragma unroll
        for (int k = 0; k < 8; ++k) { o0[k] = f2b(v[k]); o1[k] = f2b(v[8+k]); }
        unsigned short* dp = xs + (r3*34 + wi)*66 + q*16;
        *(ushort8*)dp       = o0;
        *(ushort8*)(dp + 8) = o1;
    }
    __syncthreads();

    // ---- phase 2: conv features -> Fc (swizzled) ----
    {
        const int px = tid >> 3, cg = (tid & 7) * 8;
        float a1[8], a2[8];
        #pragma unroll
        for (int k = 0; k < 8; ++k) { a1[k] = 0.f; a2[k] = 0.f; }
        #pragma unroll
        for (int t = 0; t < 9; ++t) {             // t = i2*3 + j (w-off i2, h-off j)
            const int i2 = t / 3, j = t - 3*i2;
            const ushort8 xv = *(const ushort8*)(xs + (j*34 + px + i2)*66 + cg);
            const ushort8 wv1 = *(const ushort8*)(wcvb + t*64 + cg);
            const ushort8 wv2 = *(const ushort8*)(wcvb + 576 + t*64 + cg);
            #pragma unroll
            for (int k = 0; k < 8; ++k) {
                const float xf = b2f(xv[k]);
                a1[k] = fmaf(xf, b2f(wv1[k]), a1[k]);
                a2[k] = fmaf(xf, b2f(wv2[k]), a2[k]);
            }
        }
        ushort8 o1, o2;
        #pragma unroll
        for (int k = 0; k < 8; ++k) { o1[k] = f2b(a1[k]); o2[k] = f2b(a2[k]); }
        const int sw = (px & 7) << 4;
        *(ushort8*)(smem + OFF_FC + ((px*256 + cg*2) ^ sw))       = o1;
        *(ushort8*)(smem + OFF_FC + ((px*256 + 128 + cg*2) ^ sw)) = o2;
    }
    __syncthreads();

    // ---- phase 3: GEMM1 h = relu(F . Wh^T + b); wave = o-slice, tile 2Mt x 4Ot ----
    const int l = tid & 63, wv = tid >> 6;
    const int lr = l & 15, gq = l >> 4;
    const int os = wv;

    f4 acc[2][4];
    #pragma unroll
    for (int ot = 0; ot < 4; ++ot) {
        const float bv = bh[os*64 + ot*16 + lr];
        const f4 bvv = {bv, bv, bv, bv};
        acc[0][ot] = bvv; acc[1][ot] = bvv;
    }
    #pragma unroll
    for (int ks = 0; ks < 6; ++ks) {
        short8 afr[2];
        #pragma unroll
        for (int mt = 0; mt < 2; ++mt) {
            const int px = mt*16 + lr;
            if (ks < 2)   // x-features straight from halo center row
                afr[mt] = *(const short8*)(xs + (34 + px + 1)*66 + ks*32 + gq*8);
            else          // conv features from Fc (swizzled)
                afr[mt] = *(const short8*)(smem + OFF_FC +
                            ((px*256 + (ks-2)*64 + gq*16) ^ ((px & 7) << 4)));
        }
        #pragma unroll
        for (int ot = 0; ot < 4; ++ot) {
            const short8 bfr = *(const short8*)(wtp + ((((os*4 + ot)*6 + ks)*64 + l) << 3));
            acc[0][ot] = __builtin_amdgcn_mfma_f32_16x16x32_bf16(afr[0], bfr, acc[0][ot], 0,0,0);
            acc[1][ot] = __builtin_amdgcn_mfma_f32_16x16x32_bf16(afr[1], bfr, acc[1][ot], 0,0,0);
        }
    }
    __syncthreads();   // all A-reads done; overlay h on xsb/Fc
    #pragma unroll
    for (int mt = 0; mt < 2; ++mt)
      #pragma unroll
      for (int ot = 0; ot < 4; ++ot)
        #pragma unroll
        for (int r = 0; r < 4; ++r) {
            const int px = mt*16 + gq*4 + r;
            const int o  = os*64 + ot*16 + lr;
            *(unsigned short*)(smem + ((px*512 + o*2) ^ ((px & 7) << 4))) =
                f2b(fmaxf(acc[mt][ot][r], 0.f));
        }
    __syncthreads();

    // ---- phase 4: GEMM2 dx = h . wf^T; wave = (px-half, c-half), tile 1x2 ----
    const int mt2 = wv >> 1, cs = wv & 1;
    short8 ha[8];
    #pragma unroll
    for (int ks2 = 0; ks2 < 8; ++ks2) {
        const int px = mt2*16 + lr;
        ha[ks2] = *(const short8*)(smem + ((px*512 + ks2*64 + gq*16) ^ ((px & 7) << 4)));
    }
    f4 acc2[2] = {{0.f,0.f,0.f,0.f},{0.f,0.f,0.f,0.f}};
    #pragma unroll
    for (int ks2 = 0; ks2 < 8; ++ks2) {
        #pragma unroll
        for (int ct = 0; ct < 2; ++ct) {
            const short8 bw = *(const short8*)(wfp + ((((cs*2 + ct)*8 + ks2)*64 + l) << 3));
            acc2[ct] = __builtin_amdgcn_mfma_f32_16x16x32_bf16(ha[ks2], bw, acc2[ct], 0,0,0);
        }
    }

    // ---- epilogue: gate + channel mask + life + store ----
    #pragma unroll
    for (int ct = 0; ct < 2; ++ct)
      #pragma unroll
      for (int r = 0; r < 4; ++r) {
        const int px = mt2*16 + gq*4 + r;
        const int c  = cs*32 + ct*16 + lr;
        const size_t pix = ((size_t)b*HH + h)*WW + w0 + px;
        const float life = lgs[px], g = lgs[TPX + px];
        const float dx = acc2[ct][r];
        float base;
        if (MODE == 0) base = xin[pix*64 + c];
        else base = (c < 4) ? xin[pix*64 + c] * life : src[pix*SC + (c-4)];
        const float outv = (c >= 4) ? (base + dx*g)*life : base*life;
        if (MODE == 2) dst[pix*64 + c] = outv;
        else if (c >= 4) dst[pix*SC + (c-4)] = outv;
    }
}

extern "C" void kernel_launch(void* const* d_in, const int* in_sizes, int n_in,
                              void* d_out, int out_size, void* d_ws, size_t ws_size,
                              hipStream_t stream) {
    const float* xin = (const float*)d_in[0];
    const float* w1  = (const float*)d_in[1];
    const float* w2  = (const float*)d_in[2];
    const float* wh  = (const float*)d_in[3];
    const float* bh  = (const float*)d_in[4];
    const float* wf  = (const float*)d_in[5];
    const float* rv  = (const float*)d_in[6];

    const size_t stateBytes = (size_t)NPIX * SC * 4;
    unsigned short* wtp = (unsigned short*)((char*)d_ws + stateBytes);
    unsigned short* wfp = wtp + 6144 * 8;
    float* st = (float*)d_ws;
    float* om = (float*)d_out;

    prep<<<dim3(32), dim3(256), 0, stream>>>(wh, wf, wtp, wfp);

    dim3 g(WW / TPX, HH, BB), blk(256);
    nca_step<0><<<g, blk, 0, stream>>>(xin, xin, st, wtp, wfp, w1, w2, bh, rv);
    for (int s = 1; s < 7; ++s) {
        const float* sp = (s & 1) ? (const float*)st : (const float*)om;
        float* dp       = (s & 1) ? om : st;
        nca_step<1><<<g, blk, 0, stream>>>(xin, sp, dp, wtp, wfp, w1, w2, bh, rv + (size_t)s * NPIX);
    }
    nca_step<2><<<g, blk, 0, stream>>>(xin, st, om, wtp, wfp, w1, w2, bh, rv + (size_t)7 * NPIX);
}

// Round 5
// 1136.340 us; speedup vs baseline: 64.9240x; 1.1466x over previous
//
#include <hip/hip_runtime.h>

#define BB 16
#define HH 128
#define WW 128
#define SC 60              // compact state channels (ch 4..63)
#define TPX 32             // tile width in pixels
#define NPIX (BB*HH*WW)
#define KF 192
#define HID 256

// workspace offsets (bytes)
#define WS_WTP 0u              // 98,304  : GEMM1 B-fragments bf16
#define WS_WFP 98304u          // 32,768  : GEMM2 B-fragments bf16
#define WS_WCB 131072u         //  2,304  : conv weights bf16 [2][9][64]
#define WS_AUX 133376u         // 2,097,152: aux bf16 [NPIX][4] (ch0..3 * life)
#define WS_ST  2230528u        // 62,914,560: fp32 state [NPIX][60]

typedef __attribute__((ext_vector_type(8))) short short8;
typedef __attribute__((ext_vector_type(8))) unsigned short ushort8;
typedef __attribute__((ext_vector_type(4))) float f4;

// LDS layout (bytes):
//   xsb  [3][34][66] ushort @ 0      : 13,464
//   Fc   [32][128]   ushort @ 13,472 :  8,192 (XOR-swizzled rows)
//   wcvb [2][9][64]  ushort @ 21,664 :  2,304
//   lgs  [64]        float  @ 23,968 :    256
//   h    [32][256]   ushort @ 0      : 16,384 (overlay after GEMM1)
//   stage[32][64]    float  @ 0      : <=8,192 (overlay after GEMM2 ha-loads)
#define OFF_FC  13472
#define OFF_WCV 21664
#define OFF_LG  23968
#define SMEM_SZ 24224

__device__ __forceinline__ unsigned short f2b(float f) {   // fp32 -> bf16 RTNE
    unsigned x = __float_as_uint(f);
    x += 0x7fffu + ((x >> 16) & 1u);
    return (unsigned short)(x >> 16);
}
__device__ __forceinline__ float b2f(unsigned short u) {
    return __uint_as_float(((unsigned)u) << 16);
}
__device__ __forceinline__ int refl(int i, int n) {
    if (i < 0) return -i;
    if (i >= n) return 2*n - 2 - i;
    return i;
}

// prep: weights into MFMA B-fragment order (bf16). Same layout as round 4.
__global__ __launch_bounds__(256) void prep(
    const float* __restrict__ wh, const float* __restrict__ wf,
    unsigned short* __restrict__ wtp, unsigned short* __restrict__ wfp)
{
    int i = blockIdx.x * 256 + threadIdx.x;   // 8192 groups
    if (i < 6144) {
        const int l = i & 63, r = i >> 6;
        const int ks = r % 6, r2 = r / 6;
        const int ot = r2 & 3, os = r2 >> 2;
        const int row = os*64 + ot*16 + (l & 15);
        const int k0  = ks*32 + (l >> 4)*8;
        ushort8 v;
        #pragma unroll
        for (int j = 0; j < 8; ++j) v[j] = f2b(wh[row*KF + k0 + j]);
        *(ushort8*)&wtp[(size_t)i * 8] = v;
    } else {
        const int g = i - 6144;               // 2048 groups
        const int l = g & 63, r = g >> 6;
        const int ks2 = r & 7, r2 = r >> 3;
        const int ct = r2 & 1, cs = r2 >> 1;
        const int c  = cs*32 + ct*16 + (l & 15);
        const int o0 = ks2*32 + (l >> 4)*8;
        ushort8 v;
        #pragma unroll
        for (int j = 0; j < 8; ++j) v[j] = f2b(wf[c*HID + o0 + j]);
        *(ushort8*)&wfp[(size_t)g * 8] = v;
    }
}

// prep2: conv weights -> bf16 [filter][tap][ch] (verified mapping from r2-r4)
__global__ __launch_bounds__(256) void prep2(
    const float* __restrict__ w1, const float* __restrict__ w2,
    unsigned short* __restrict__ wcb)
{
    int i = blockIdx.x * 256 + threadIdx.x;
    if (i < 1152) {
        const int f = i / 576, rem = i - f * 576;
        const int t = rem >> 6, c = rem & 63;
        wcb[i] = f2b((f ? w2 : w1)[c*9 + t]);
    }
}

// SRCF: 0 = src is xin (64ch fp32 raw, first step), 1 = src is state60 + aux
// DSTF: 0 = dst is state60 (+ write aux if SRCF==0), 1 = dst is out (64ch fp32)
template<int SRCF, int DSTF>
__global__ __launch_bounds__(256, 6) void nca_step(
    const float* __restrict__ src, unsigned short* __restrict__ aux,
    float* __restrict__ dst,
    const unsigned short* __restrict__ wtp, const unsigned short* __restrict__ wfp,
    const unsigned short* __restrict__ wcbg,
    const float* __restrict__ bh, const float* __restrict__ rnd)
{
    __shared__ __align__(16) char smem[SMEM_SZ];
    unsigned short* xs   = (unsigned short*)smem;
    unsigned short* wcvb = (unsigned short*)(smem + OFF_WCV);
    float*          lgs  = (float*)(smem + OFF_LG);
    float*          stageF = (float*)smem;

    const int tid = threadIdx.x;
    // XCD-aware swizzle: xcd = d&7 owns a contiguous 256-row slab (m204-bijective)
    {
    }
    const int d  = blockIdx.x;
    const int ii = d >> 3;
    const int R  = (d & 7) * 256 + (ii >> 2);   // global row index b*128+h
    const int w0 = (ii & 3) * TPX;
    const int h  = R & 127;
    const int b  = R >> 7;

    // ---- phase 1: conv weights (L2), life/gate, halo -> bf16 LDS ----
    for (int j = tid; j < 144; j += 256)
        ((ushort8*)wcvb)[j] = ((const ushort8*)wcbg)[j];
    if (tid < TPX) {
        const size_t pix = (size_t)R * WW + w0 + tid;
        float lf;
        if (SRCF == 0) lf = (src[pix*64] > 0.f) ? 1.f : 0.f;
        else           lf = (b2f(aux[pix*4]) > 0.f) ? 1.f : 0.f;
        lgs[tid]       = lf;
        lgs[TPX + tid] = (rnd[pix] > 0.5f) ? 1.f : 0.f;
    }
    for (int s0 = tid >> 2; s0 < 102; s0 += 64) {
        const int r3 = s0 / 34, wi = s0 - r3*34;
        const int q = tid & 3;                    // 16-channel group
        const int sr = refl(h - 1 + r3, HH);
        const int sc = refl(w0 - 1 + wi, WW);
        const size_t pix = ((size_t)b*HH + sr)*WW + sc;
        ushort8 o0, o1;
        if (SRCF == 0) {
            const float* p = src + pix*64 + q*16;
            f4 a0 = *(const f4*)p, a1 = *(const f4*)(p+4);
            f4 a2 = *(const f4*)(p+8), a3 = *(const f4*)(p+12);
            o0[0]=f2b(a0.x); o0[1]=f2b(a0.y); o0[2]=f2b(a0.z); o0[3]=f2b(a0.w);
            o0[4]=f2b(a1.x); o0[5]=f2b(a1.y); o0[6]=f2b(a1.z); o0[7]=f2b(a1.w);
            o1[0]=f2b(a2.x); o1[1]=f2b(a2.y); o1[2]=f2b(a2.z); o1[3]=f2b(a2.w);
            o1[4]=f2b(a3.x); o1[5]=f2b(a3.y); o1[6]=f2b(a3.z); o1[7]=f2b(a3.w);
        } else if (q == 0) {
            const uint2 av = *(const uint2*)(aux + pix*4);   // ch0..3 pre-bf16
            o0[0] = (unsigned short)(av.x & 0xffff);
            o0[1] = (unsigned short)(av.x >> 16);
            o0[2] = (unsigned short)(av.y & 0xffff);
            o0[3] = (unsigned short)(av.y >> 16);
            const float* p = src + pix*SC;                   // state ch4..15
            f4 a0 = *(const f4*)p, a1 = *(const f4*)(p+4), a2 = *(const f4*)(p+8);
            o0[4]=f2b(a0.x); o0[5]=f2b(a0.y); o0[6]=f2b(a0.z); o0[7]=f2b(a0.w);
            o1[0]=f2b(a1.x); o1[1]=f2b(a1.y); o1[2]=f2b(a1.z); o1[3]=f2b(a1.w);
            o1[4]=f2b(a2.x); o1[5]=f2b(a2.y); o1[6]=f2b(a2.z); o1[7]=f2b(a2.w);
        } else {
            const float* p = src + pix*SC + q*16 - 4;
            f4 a0 = *(const f4*)p, a1 = *(const f4*)(p+4);
            f4 a2 = *(const f4*)(p+8), a3 = *(const f4*)(p+12);
            o0[0]=f2b(a0.x); o0[1]=f2b(a0.y); o0[2]=f2b(a0.z); o0[3]=f2b(a0.w);
            o0[4]=f2b(a1.x); o0[5]=f2b(a1.y); o0[6]=f2b(a1.z); o0[7]=f2b(a1.w);
            o1[0]=f2b(a2.x); o1[1]=f2b(a2.y); o1[2]=f2b(a2.z); o1[3]=f2b(a2.w);
            o1[4]=f2b(a3.x); o1[5]=f2b(a3.y); o1[6]=f2b(a3.z); o1[7]=f2b(a3.w);
        }
        unsigned short* dp = xs + (r3*34 + wi)*66 + q*16;
        *(ushort8*)dp       = o0;
        *(ushort8*)(dp + 8) = o1;
    }
    __syncthreads();                                          // B1

    // ---- phase 2: conv features -> Fc (swizzled) ----
    {
        const int px = tid >> 3, cg = (tid & 7) * 8;
        float a1[8], a2[8];
        #pragma unroll
        for (int k = 0; k < 8; ++k) { a1[k] = 0.f; a2[k] = 0.f; }
        #pragma unroll
        for (int t = 0; t < 9; ++t) {             // t = i2*3 + j
            const int i2 = t / 3, j = t - 3*i2;
            const ushort8 xv  = *(const ushort8*)(xs + (j*34 + px + i2)*66 + cg);
            const ushort8 wv1 = *(const ushort8*)(wcvb + t*64 + cg);
            const ushort8 wv2 = *(const ushort8*)(wcvb + 576 + t*64 + cg);
            #pragma unroll
            for (int k = 0; k < 8; ++k) {
                const float xf = b2f(xv[k]);
                a1[k] = fmaf(xf, b2f(wv1[k]), a1[k]);
                a2[k] = fmaf(xf, b2f(wv2[k]), a2[k]);
            }
        }
        ushort8 o1, o2;
        #pragma unroll
        for (int k = 0; k < 8; ++k) { o1[k] = f2b(a1[k]); o2[k] = f2b(a2[k]); }
        const int sw = (px & 7) << 4;
        *(ushort8*)(smem + OFF_FC + ((px*256 + cg*2) ^ sw))       = o1;
        *(ushort8*)(smem + OFF_FC + ((px*256 + 128 + cg*2) ^ sw)) = o2;
    }
    __syncthreads();                                          // B2

    // ---- phase 3: GEMM1 h = relu(F . Wh^T + b); wave = o-slice, tile 2Mt x 4Ot ----
    const int l = tid & 63, wv = tid >> 6;
    const int lr = l & 15, gq = l >> 4;
    const int os = wv;

    f4 acc[2][4];
    #pragma unroll
    for (int ot = 0; ot < 4; ++ot) {
        const float bv = bh[os*64 + ot*16 + lr];
        const f4 bvv = {bv, bv, bv, bv};
        acc[0][ot] = bvv; acc[1][ot] = bvv;
    }
    #pragma unroll
    for (int ks = 0; ks < 6; ++ks) {
        short8 afr[2];
        #pragma unroll
        for (int mt = 0; mt < 2; ++mt) {
            const int px = mt*16 + lr;
            if (ks < 2)
                afr[mt] = *(const short8*)(xs + (34 + px + 1)*66 + ks*32 + gq*8);
            else
                afr[mt] = *(const short8*)(smem + OFF_FC +
                            ((px*256 + (ks-2)*64 + gq*16) ^ ((px & 7) << 4)));
        }
        #pragma unroll
        for (int ot = 0; ot < 4; ++ot) {
            const short8 bfr = *(const short8*)(wtp + ((((os*4 + ot)*6 + ks)*64 + l) << 3));
            acc[0][ot] = __builtin_amdgcn_mfma_f32_16x16x32_bf16(afr[0], bfr, acc[0][ot], 0,0,0);
            acc[1][ot] = __builtin_amdgcn_mfma_f32_16x16x32_bf16(afr[1], bfr, acc[1][ot], 0,0,0);
        }
    }
    __syncthreads();                                          // B3

    // prefetch epilogue base values (global fp32) — hides under h-store/GEMM2
    const int mt2 = wv >> 1, cs = wv & 1;
    float basev[8];
    #pragma unroll
    for (int ct = 0; ct < 2; ++ct)
      #pragma unroll
      for (int r = 0; r < 4; ++r) {
        const int px = mt2*16 + gq*4 + r;
        const int c  = cs*32 + ct*16 + lr;
        const size_t pix = (size_t)R * WW + w0 + px;
        float bvv;
        if (SRCF == 0)      bvv = src[pix*64 + c];
        else if (c >= 4)    bvv = src[pix*SC + (c-4)];
        else                bvv = b2f(aux[pix*4 + c]);
        basev[ct*4 + r] = bvv;
      }

    // relu + bf16 h into LDS (overlay), swizzled rows of 512 B
    #pragma unroll
    for (int mt = 0; mt < 2; ++mt)
      #pragma unroll
      for (int ot = 0; ot < 4; ++ot)
        #pragma unroll
        for (int r = 0; r < 4; ++r) {
            const int px = mt*16 + gq*4 + r;
            const int o  = os*64 + ot*16 + lr;
            *(unsigned short*)(smem + ((px*512 + o*2) ^ ((px & 7) << 4))) =
                f2b(fmaxf(acc[mt][ot][r], 0.f));
        }
    __syncthreads();                                          // B4

    // ---- phase 4: GEMM2 dx = h . wf^T ----
    short8 ha[8];
    #pragma unroll
    for (int ks2 = 0; ks2 < 8; ++ks2) {
        const int px = mt2*16 + lr;
        ha[ks2] = *(const short8*)(smem + ((px*512 + ks2*64 + gq*16) ^ ((px & 7) << 4)));
    }
    __syncthreads();                                          // B5 (h dead after this)

    f4 acc2[2] = {{0.f,0.f,0.f,0.f},{0.f,0.f,0.f,0.f}};
    #pragma unroll
    for (int ks2 = 0; ks2 < 8; ++ks2) {
        #pragma unroll
        for (int ct = 0; ct < 2; ++ct) {
            const short8 bw = *(const short8*)(wfp + ((((cs*2 + ct)*8 + ks2)*64 + l) << 3));
            acc2[ct] = __builtin_amdgcn_mfma_f32_16x16x32_bf16(ha[ks2], bw, acc2[ct], 0,0,0);
        }
    }

    // ---- epilogue: gate + mask + life -> LDS stage ----
    #pragma unroll
    for (int ct = 0; ct < 2; ++ct)
      #pragma unroll
      for (int r = 0; r < 4; ++r) {
        const int px = mt2*16 + gq*4 + r;
        const int c  = cs*32 + ct*16 + lr;
        const float life = lgs[px], g = lgs[TPX + px];
        const float base = basev[ct*4 + r];
        float outv;
        if (c >= 4) outv = (base + acc2[ct][r] * g) * life;
        else        outv = base * life;
        if (DSTF == 1)      stageF[px*64 + c] = outv;
        else if (c >= 4)    stageF[px*SC + (c-4)] = outv;
        if (SRCF == 0 && DSTF == 0 && c < 4) {
            const size_t pix = (size_t)R * WW + w0 + px;
            aux[pix*4 + c] = f2b(outv);       // constant across steps
        }
      }
    __syncthreads();                                          // B6

    // ---- coalesced full-line store ----
    const size_t pix0 = (size_t)R * WW + w0;
    if (DSTF == 1) {
        float* dbase = dst + pix0 * 64;
        for (int i = tid; i < 512; i += 256)
            *(f4*)(dbase + i*4) = *(const f4*)(stageF + i*4);
    } else {
        float* dbase = dst + pix0 * SC;
        for (int i = tid; i < 480; i += 256)
            *(f4*)(dbase + i*4) = *(const f4*)(stageF + i*4);
    }
}

extern "C" void kernel_launch(void* const* d_in, const int* in_sizes, int n_in,
                              void* d_out, int out_size, void* d_ws, size_t ws_size,
                              hipStream_t stream) {
    const float* xin = (const float*)d_in[0];
    const float* w1  = (const float*)d_in[1];
    const float* w2  = (const float*)d_in[2];
    const float* wh  = (const float*)d_in[3];
    const float* bh  = (const float*)d_in[4];
    const float* wf  = (const float*)d_in[5];
    const float* rv  = (const float*)d_in[6];

    unsigned short* wtp = (unsigned short*)((char*)d_ws + WS_WTP);
    unsigned short* wfp = (unsigned short*)((char*)d_ws + WS_WFP);
    unsigned short* wcb = (unsigned short*)((char*)d_ws + WS_WCB);
    unsigned short* aux = (unsigned short*)((char*)d_ws + WS_AUX);
    float* st = (float*)((char*)d_ws + WS_ST);
    float* om = (float*)d_out;     // 60ch scratch during s1..s6; 64ch final at s7

    prep <<<dim3(32), dim3(256), 0, stream>>>(wh, wf, wtp, wfp);
    prep2<<<dim3(5),  dim3(256), 0, stream>>>(w1, w2, wcb);

    dim3 g(8192), blk(256);
    nca_step<0,0><<<g, blk, 0, stream>>>(xin, aux, st, wtp, wfp, wcb, bh, rv);
    for (int s = 1; s < 7; ++s) {
        const float* sp = (s & 1) ? st : om;
        float* dp       = (s & 1) ? om : st;
        nca_step<1,0><<<g, blk, 0, stream>>>(sp, aux, dp, wtp, wfp, wcb, bh,
                                             rv + (size_t)s * NPIX);
    }
    nca_step<1,1><<<g, blk, 0, stream>>>(st, aux, om, wtp, wfp, wcb, bh,
                                         rv + (size_t)7 * NPIX);
}